// Round 3
// baseline (4286.808 us; speedup 1.0000x reference)
//
#include <hip/hip_runtime.h>
#include <math.h>

#define AGENTS 128
#define DIM 256
#define NHEADS 8
#define MEM_LEN 1024
#define MLP_DIM 1024
#define PRED 12
#define MAXS (PRED * AGENTS)   // 1536

typedef __attribute__((ext_vector_type(8))) short short8;
typedef __attribute__((ext_vector_type(4))) float f32x4;

#define MFMA(a, b, c) __builtin_amdgcn_mfma_f32_16x16x32_bf16(a, b, c, 0, 0, 0)

__device__ __forceinline__ unsigned short f2bf(float f) {
  union { float f; unsigned u; } v; v.f = f;
  unsigned r = v.u + 0x7fffu + ((v.u >> 16) & 1u);   // RNE
  return (unsigned short)(r >> 16);
}

__device__ __forceinline__ float dot4(float4 a, float4 b) {
  return a.x * b.x + a.y * b.y + a.z * b.z + a.w * b.w;
}

// pack 8 consecutive fp32 -> bf16 frag (works for global or LDS pointers)
__device__ __forceinline__ short8 afrag8(const float* p) {
  float4 a = *(const float4*)p;
  float4 b = *(const float4*)(p + 4);
  short8 r;
  r[0] = (short)f2bf(a.x); r[1] = (short)f2bf(a.y);
  r[2] = (short)f2bf(a.z); r[3] = (short)f2bf(a.w);
  r[4] = (short)f2bf(b.x); r[5] = (short)f2bf(b.y);
  r[6] = (short)f2bf(b.z); r[7] = (short)f2bf(b.w);
  return r;
}

// LayerNorm of 16 rows resident in sx; optionally mirror result to global.
__device__ __forceinline__ void ln16(float (*sx)[264], const float* __restrict__ g,
                                     const float* __restrict__ b, int w, int l,
                                     float* __restrict__ gout, int row0)
{
#pragma unroll
  for (int rr = 0; rr < 4; ++rr) {
    int row = w * 4 + rr;
    float4 v = *(const float4*)&sx[row][l * 4];
    float s = v.x + v.y + v.z + v.w;
#pragma unroll
    for (int o = 32; o > 0; o >>= 1) s += __shfl_xor(s, o, 64);
    float mean = s * (1.0f / 256.0f);
    float dx = v.x - mean, dy = v.y - mean, dz = v.z - mean, dw = v.w - mean;
    float s2 = dx * dx + dy * dy + dz * dz + dw * dw;
#pragma unroll
    for (int o = 32; o > 0; o >>= 1) s2 += __shfl_xor(s2, o, 64);
    float rstd = rsqrtf(s2 * (1.0f / 256.0f) + 1e-5f);
    float4 gg = *(const float4*)&g[l * 4];
    float4 bb = *(const float4*)&b[l * 4];
    float4 o4 = make_float4(dx * rstd * gg.x + bb.x, dy * rstd * gg.y + bb.y,
                            dz * rstd * gg.z + bb.z, dw * rstd * gg.w + bb.w);
    *(float4*)&sx[row][l * 4] = o4;
    if (gout) *(float4*)&gout[(row0 + row) * DIM + l * 4] = o4;
  }
}

// 16 rows x 256 cols projection from cached A-frags; row-major output.
__device__ __forceinline__ void proj_row(
    const short8 afr[8], const unsigned short* __restrict__ W,
    const float* __restrict__ b, float* __restrict__ o, int row0, int w, int l)
{
  const int c15 = l & 15, kl8 = (l >> 4) * 8, r0 = (l >> 4) * 4;
  f32x4 acc[4] = {};
  const unsigned short* wp = W + (w * 64 + c15) * 256 + kl8;
#pragma unroll
  for (int kc = 0; kc < 8; ++kc)
#pragma unroll
    for (int t = 0; t < 4; ++t)
      acc[t] = MFMA(afr[kc], *(const short8*)(wp + t * 16 * 256 + kc * 32), acc[t]);
#pragma unroll
  for (int t = 0; t < 4; ++t) {
    int c = w * 64 + t * 16 + c15;
    float bb = b[c];
#pragma unroll
    for (int r = 0; r < 4; ++r)
      o[(row0 + r0 + r) * DIM + c] = acc[t][r] + bb;
  }
}

// Same, but output head-major [h][time][32] (K/V caches).
__device__ __forceinline__ void proj_headmajor(
    const short8 afr[8], const unsigned short* __restrict__ W,
    const float* __restrict__ b, float* __restrict__ o,
    int sstride, int row0, int w, int l)
{
  const int c15 = l & 15, kl8 = (l >> 4) * 8, r0 = (l >> 4) * 4;
  f32x4 acc[4] = {};
  const unsigned short* wp = W + (w * 64 + c15) * 256 + kl8;
#pragma unroll
  for (int kc = 0; kc < 8; ++kc)
#pragma unroll
    for (int t = 0; t < 4; ++t)
      acc[t] = MFMA(afr[kc], *(const short8*)(wp + t * 16 * 256 + kc * 32), acc[t]);
#pragma unroll
  for (int t = 0; t < 4; ++t) {
    int c = w * 64 + t * 16 + c15;
    int h = c >> 5, wi = c & 31;
    float bb = b[c];
#pragma unroll
    for (int r = 0; r < 4; ++r)
      o[h * sstride * 32 + (row0 + r0 + r) * 32 + wi] = acc[t][r] + bb;
  }
}

// ---------------------------------------------------------------------------
// Embed + fused layer0 SA-QKV. Grid (8).
// ---------------------------------------------------------------------------
__global__ __launch_bounds__(256) void embed_k(
    const float* __restrict__ scene, const float* __restrict__ ds,
    const unsigned short* __restrict__ inWb, const float* __restrict__ inb,
    const float* __restrict__ peA, const float* __restrict__ peT,
    float* __restrict__ x, int step,
    const unsigned short* __restrict__ Wq, const float* __restrict__ bq, float* __restrict__ qout,
    const unsigned short* __restrict__ Wk, const float* __restrict__ bk, float* __restrict__ kout,
    const unsigned short* __restrict__ Wv, const float* __restrict__ bv, float* __restrict__ vout,
    int sstride)
{
  __shared__ float sx[16][264];
  const int tid = threadIdx.x, l = tid & 63, w = tid >> 6;
  const int c15 = l & 15, kl8 = (l >> 4) * 8, r0 = (l >> 4) * 4;
  const int row0 = blockIdx.x * 16;
  const int mrow = row0 + c15;
  f32x4 acc[4] = {};
  for (int k0 = 0; k0 < 160; k0 += 32) {
    short8 af;
#pragma unroll
    for (int j = 0; j < 8; ++j) {
      int kk = k0 + kl8 + j;
      float v = (kk < 2) ? scene[mrow * 2 + kk]
                         : ((kk < 130) ? ds[mrow * 128 + (kk - 2)] : 0.f);
      af[j] = (short)f2bf(v);
    }
    const unsigned short* wp = inWb + (w * 64 + c15) * 160 + k0 + kl8;
#pragma unroll
    for (int t = 0; t < 4; ++t)
      acc[t] = MFMA(af, *(const short8*)(wp + t * 16 * 160), acc[t]);
  }
#pragma unroll
  for (int t = 0; t < 4; ++t) {
    int c = w * 64 + t * 16 + c15;
    float bb = inb[c] + peT[step * DIM + c];
#pragma unroll
    for (int r = 0; r < 4; ++r) {
      int row = row0 + r0 + r;
      float v = acc[t][r] + bb + peA[row * DIM + c];
      sx[r0 + r][c] = v;
      x[row * DIM + c] = v;
    }
  }
  __syncthreads();
  short8 afr[8];
#pragma unroll
  for (int kc = 0; kc < 8; ++kc) afr[kc] = afrag8(&sx[c15][kc * 32 + kl8]);
  proj_row(afr, Wq, bq, qout, row0, w, l);
  proj_headmajor(afr, Wk, bk, kout, sstride, row0, w, l);
  proj_headmajor(afr, Wv, bv, vout, sstride, row0, w, l);
}

// ---------------------------------------------------------------------------
// Attention: grid (AGENTS, NHEADS), 64 threads (1 wave). K/V head-major fp32.
// ---------------------------------------------------------------------------
__global__ __launch_bounds__(64) void attn_k(
    const float* __restrict__ Q, const float* __restrict__ Kc,
    const float* __restrict__ Vc, const float* __restrict__ mask,
    float* __restrict__ O, int S, int sstride)
{
  __shared__ float wl[MAXS];
  const int i = blockIdx.x, h = blockIdx.y, lane = threadIdx.x;

  float4 q[8];
  const float4* qp = (const float4*)(Q + i * DIM + h * 32);
#pragma unroll
  for (int e = 0; e < 8; ++e) q[e] = qp[e];
  const float m0 = mask[i * AGENTS + lane];
  const float m1 = mask[i * AGENTS + 64 + lane];

  const float4* kh = (const float4*)(Kc + h * sstride * 32);
  const float scale = 0.17677669529663687f;  // 1/sqrt(32)
  float lmax = -1e30f;
  const int nit = S >> 6;
  for (int it = 0; it < nit; ++it) {
    int j = it * 64 + lane;
    const float4* kr = kh + j * 8;
    float d = 0.f;
#pragma unroll
    for (int e = 0; e < 8; ++e) d += dot4(q[e], kr[e]);
    d = d * scale + ((it & 1) ? m1 : m0);
    wl[j] = d;
    lmax = fmaxf(lmax, d);
  }
#pragma unroll
  for (int o = 32; o > 0; o >>= 1) lmax = fmaxf(lmax, __shfl_xor(lmax, o, 64));

  float lsum = 0.f;
  for (int it = 0; it < nit; ++it) {
    int j = it * 64 + lane;
    float e = expf(wl[j] - lmax);
    wl[j] = e;
    lsum += e;
  }
#pragma unroll
  for (int o = 32; o > 0; o >>= 1) lsum += __shfl_xor(lsum, o, 64);
  const float inv = 1.0f / lsum;
  __syncthreads();

  // PV: 8 row-groups x 8 float4 column-groups
  const int c4 = lane & 7, rg = lane >> 3;
  const float4* vh = (const float4*)(Vc + h * sstride * 32);
  float4 acc = make_float4(0.f, 0.f, 0.f, 0.f);
  for (int j = rg; j < S; j += 8) {
    float ww = wl[j];
    float4 v4 = vh[j * 8 + c4];
    acc.x += ww * v4.x; acc.y += ww * v4.y;
    acc.z += ww * v4.z; acc.w += ww * v4.w;
  }
#pragma unroll
  for (int off = 8; off <= 32; off <<= 1) {
    acc.x += __shfl_xor(acc.x, off, 64); acc.y += __shfl_xor(acc.y, off, 64);
    acc.z += __shfl_xor(acc.z, off, 64); acc.w += __shfl_xor(acc.w, off, 64);
  }
  if (rg == 0)
    *(float4*)(O + i * DIM + h * 32 + c4 * 4) =
        make_float4(acc.x * inv, acc.y * inv, acc.z * inv, acc.w * inv);
}

// ---------------------------------------------------------------------------
// SA out-proj + LN1 + fused CA-Q projection. Grid (8).
// ---------------------------------------------------------------------------
__global__ __launch_bounds__(256) void oln_k(
    const float* __restrict__ Ain, const unsigned short* __restrict__ Wo,
    const float* __restrict__ bo, const float* __restrict__ resid,
    const float* __restrict__ g, const float* __restrict__ bv,
    float* __restrict__ xout,
    const unsigned short* __restrict__ Wq, const float* __restrict__ bq,
    float* __restrict__ qout)
{
  __shared__ float sx[16][264];
  const int tid = threadIdx.x, l = tid & 63, w = tid >> 6;
  const int c15 = l & 15, kl8 = (l >> 4) * 8, r0 = (l >> 4) * 4;
  const int row0 = blockIdx.x * 16;
  f32x4 acc[4] = {};
  const float* arow = Ain + (row0 + c15) * 256 + kl8;
  const unsigned short* wp = Wo + (w * 64 + c15) * 256 + kl8;
  for (int k0 = 0; k0 < 256; k0 += 32) {
    short8 af = afrag8(arow + k0);
#pragma unroll
    for (int t = 0; t < 4; ++t)
      acc[t] = MFMA(af, *(const short8*)(wp + t * 16 * 256 + k0), acc[t]);
  }
#pragma unroll
  for (int t = 0; t < 4; ++t) {
    int c = w * 64 + t * 16 + c15;
    float bb = bo[c];
#pragma unroll
    for (int r = 0; r < 4; ++r)
      sx[r0 + r][c] = acc[t][r] + bb + resid[(row0 + r0 + r) * DIM + c];
  }
  __syncthreads();
  ln16(sx, g, bv, w, l, xout, row0);
  __syncthreads();
  short8 afr[8];
#pragma unroll
  for (int kc = 0; kc < 8; ++kc) afr[kc] = afrag8(&sx[c15][kc * 32 + kl8]);
  proj_row(afr, Wq, bq, qout, row0, w, l);
}

// ---------------------------------------------------------------------------
// Fused: CA out-proj + LN2 + FF1(relu) + FF2 + LN3 [+ QKV(l+1) | + out-proj].
// Grid (8). mid activations live in LDS bf16 [16][1032] (pad -> 2-way free).
// ---------------------------------------------------------------------------
template <bool QKV, bool OUTP>
__global__ __launch_bounds__(256) void ffn_k(
    const float* __restrict__ Ain, const unsigned short* __restrict__ Wo,
    const float* __restrict__ bo, const float* __restrict__ resid,
    const float* __restrict__ g2, const float* __restrict__ b2v,
    const unsigned short* __restrict__ W1, const float* __restrict__ b1v,
    const unsigned short* __restrict__ W2, const float* __restrict__ b2f,
    const float* __restrict__ g3, const float* __restrict__ b3v,
    float* __restrict__ xout,
    const unsigned short* __restrict__ Wq, const float* __restrict__ bq, float* __restrict__ qout,
    const unsigned short* __restrict__ Wk, const float* __restrict__ bk, float* __restrict__ kout,
    const unsigned short* __restrict__ Wv, const float* __restrict__ bv, float* __restrict__ vout,
    int sstride,
    const float* __restrict__ outW, const float* __restrict__ outB,
    float* __restrict__ outbuf, float* __restrict__ scene, int step)
{
  __shared__ float sx[16][264];
  __shared__ unsigned short smid[16][1032];
  const int tid = threadIdx.x, l = tid & 63, w = tid >> 6;
  const int c15 = l & 15, kl8 = (l >> 4) * 8, r0 = (l >> 4) * 4;
  const int row0 = blockIdx.x * 16;

  // A: CA out-proj + bias + residual -> sx
  {
    f32x4 acc[4] = {};
    const float* arow = Ain + (row0 + c15) * 256 + kl8;
    const unsigned short* wp = Wo + (w * 64 + c15) * 256 + kl8;
    for (int k0 = 0; k0 < 256; k0 += 32) {
      short8 af = afrag8(arow + k0);
#pragma unroll
      for (int t = 0; t < 4; ++t)
        acc[t] = MFMA(af, *(const short8*)(wp + t * 16 * 256 + k0), acc[t]);
    }
#pragma unroll
    for (int t = 0; t < 4; ++t) {
      int c = w * 64 + t * 16 + c15;
      float bb = bo[c];
#pragma unroll
      for (int r = 0; r < 4; ++r)
        sx[r0 + r][c] = acc[t][r] + bb + resid[(row0 + r0 + r) * DIM + c];
    }
  }
  __syncthreads();
  // B: LN2 (LDS only)
  ln16(sx, g2, b2v, w, l, nullptr, row0);
  __syncthreads();
  // C: FF1 + relu -> smid (bf16). Wave w owns cols [w*256, w*256+256).
  {
    short8 afr[8];
#pragma unroll
    for (int kc = 0; kc < 8; ++kc) afr[kc] = afrag8(&sx[c15][kc * 32 + kl8]);
#pragma unroll 4
    for (int t = 0; t < 16; ++t) {
      f32x4 acc = {};
      const unsigned short* wp = W1 + (w * 256 + t * 16 + c15) * 256 + kl8;
#pragma unroll
      for (int kc = 0; kc < 8; ++kc)
        acc = MFMA(afr[kc], *(const short8*)(wp + kc * 32), acc);
      int c = w * 256 + t * 16 + c15;
      float bb = b1v[c];
#pragma unroll
      for (int r = 0; r < 4; ++r)
        smid[r0 + r][c] = f2bf(fmaxf(acc[r] + bb, 0.f));
    }
  }
  __syncthreads();
  // D: FF2 (K=1024) from smid
  f32x4 facc[4] = {};
  for (int kc = 0; kc < 4; ++kc) {
    short8 afr[8];
#pragma unroll
    for (int kk = 0; kk < 8; ++kk)
      afr[kk] = *(const short8*)&smid[c15][kc * 256 + kk * 32 + kl8];
    const unsigned short* wp = W2 + (w * 64 + c15) * 1024 + kc * 256 + kl8;
#pragma unroll
    for (int t = 0; t < 4; ++t)
#pragma unroll
      for (int kk = 0; kk < 8; ++kk)
        facc[t] = MFMA(afr[kk], *(const short8*)(wp + t * 16 * 1024 + kk * 32), facc[t]);
  }
  // E: + bias + residual(LN2-out in sx), then LN3
#pragma unroll
  for (int t = 0; t < 4; ++t) {
    int c = w * 64 + t * 16 + c15;
    float bb = b2f[c];
#pragma unroll
    for (int r = 0; r < 4; ++r)
      sx[r0 + r][c] = facc[t][r] + bb + sx[r0 + r][c];
  }
  __syncthreads();
  ln16(sx, g3, b3v, w, l, xout, row0);
  __syncthreads();
  // F: fused tail
  if (QKV) {
    short8 afr[8];
#pragma unroll
    for (int kc = 0; kc < 8; ++kc) afr[kc] = afrag8(&sx[c15][kc * 32 + kl8]);
    proj_row(afr, Wq, bq, qout, row0, w, l);
    proj_headmajor(afr, Wk, bk, kout, sstride, row0, w, l);
    proj_headmajor(afr, Wv, bv, vout, sstride, row0, w, l);
  }
  if (OUTP) {
    // 256 threads: (row 0..15) x (outcol 0..1) x (k-chunk 0..7)
    int il = tid >> 4, jj = (tid >> 3) & 1, kc = tid & 7;
    float a = 0.f;
    const float* sxr = &sx[il][kc * 32];
    const float* wr = outW + jj * 256 + kc * 32;
#pragma unroll
    for (int k = 0; k < 32; ++k) a += sxr[k] * wr[k];
#pragma unroll
    for (int off = 4; off > 0; off >>= 1) a += __shfl_xor(a, off, 64);
    if (kc == 0) {
      a += outB[jj];
      int gi = row0 + il;
      outbuf[(step * AGENTS + gi) * 2 + jj] = a;
      scene[gi * 2 + jj] += a;
    }
  }
}

// ---------------------------------------------------------------------------
// memory K/V precompute (head-major): grid (64,1,4); z = layer*2 + (0=K,1=V).
// ---------------------------------------------------------------------------
__global__ __launch_bounds__(256) void memkv_k(
    const float* __restrict__ mem, const unsigned short* __restrict__ dxd,
    const float* __restrict__ bk, const float* __restrict__ bvv,
    float* __restrict__ memK, float* __restrict__ memV)
{
  const int z = blockIdx.z, li = z >> 1, which = z & 1;
  const unsigned short* W = dxd + (5 + which) * 131072 + li * 65536;
  const float* b = (which ? bvv : bk) + li * 256;
  float* o = (which ? memV : memK) + li * MEM_LEN * DIM;
  const int tid = threadIdx.x, l = tid & 63, w = tid >> 6;
  const int c15 = l & 15, kl8 = (l >> 4) * 8, r0 = (l >> 4) * 4;
  const int row0 = blockIdx.x * 16;
  f32x4 acc[4] = {};
  const float* arow = mem + (row0 + c15) * 256 + kl8;
  const unsigned short* wp = W + (w * 64 + c15) * 256 + kl8;
  for (int k0 = 0; k0 < 256; k0 += 32) {
    short8 af = afrag8(arow + k0);
#pragma unroll
    for (int t = 0; t < 4; ++t)
      acc[t] = MFMA(af, *(const short8*)(wp + t * 16 * 256 + k0), acc[t]);
  }
#pragma unroll
  for (int t = 0; t < 4; ++t) {
    int c = w * 64 + t * 16 + c15;
    int h = c >> 5, wi = c & 31;
    float bb = b[c];
#pragma unroll
    for (int r = 0; r < 4; ++r)
      o[h * MEM_LEN * 32 + (row0 + r0 + r) * 32 + wi] = acc[t][r] + bb;
  }
}

// ---------------------------------------------------------------------------
// Prologue converters / tables
// ---------------------------------------------------------------------------
__global__ void cvt8_k(const float* p0, const float* p1, const float* p2,
                       const float* p3, const float* p4, const float* p5,
                       const float* p6, const float* p7, unsigned short* dst)
{
  const float* s;
  switch (blockIdx.z) {
    case 0: s = p0; break; case 1: s = p1; break;
    case 2: s = p2; break; case 3: s = p3; break;
    case 4: s = p4; break; case 5: s = p5; break;
    case 6: s = p6; break; default: s = p7; break;
  }
  int i = blockIdx.x * 256 + threadIdx.x;
  dst[blockIdx.z * 131072 + i] = f2bf(s[i]);
}

__global__ void cvtff_k(const float* w1, const float* w2, unsigned short* dst)
{
  const float* s = blockIdx.z ? w2 : w1;
  int i = blockIdx.x * 256 + threadIdx.x;
  dst[blockIdx.z * 524288 + i] = f2bf(s[i]);
}

__global__ void cvtinw_k(const float* w, unsigned short* dst)
{
  int i = blockIdx.x * 256 + threadIdx.x;
  if (i >= 256 * 160) return;
  int n = i / 160, k = i - n * 160;
  dst[i] = (k < 130) ? f2bf(w[n * 130 + k]) : (unsigned short)0;
}

__global__ void pe_k(float* peA, float* peT)
{
  int i = blockIdx.x * 256 + threadIdx.x;
  if (i < 128 * 256) {
    int row = i >> 8, c = i & 255, p = c >> 1;
    float dv = expf((float)(2 * p) * (-9.210340371976184f / 256.f));
    float ang = (float)row * dv;
    peA[i] = (c & 1) ? cosf(ang) : sinf(ang);
  } else if (i < 140 * 256) {
    int j = i - 32768;
    int s = j >> 8, c = j & 255, p = c >> 1;
    float dv = expf((float)(2 * p) * (-9.210340371976184f / 256.f));
    float ang = (float)s * dv;
    peT[j] = (c & 1) ? cosf(ang) : sinf(ang);
  }
}

// ---------------------------------------------------------------------------
extern "C" void kernel_launch(void* const* d_in, const int* in_sizes, int n_in,
                              void* d_out, int out_size, void* d_ws, size_t ws_size,
                              hipStream_t stream)
{
  const float* last_pos      = (const float*)d_in[0];
  const float* decoder_state = (const float*)d_in[1];
  const float* memory        = (const float*)d_in[2];
  const float* agent_mask    = (const float*)d_in[3];
  const float* in_W  = (const float*)d_in[4];
  const float* in_b  = (const float*)d_in[5];
  const float* out_W = (const float*)d_in[6];
  const float* out_b = (const float*)d_in[7];
  const float* sa_bq = (const float*)d_in[9];
  const float* sa_bk = (const float*)d_in[11];
  const float* sa_bv = (const float*)d_in[13];
  const float* sa_bo = (const float*)d_in[15];
  const float* ca_bq = (const float*)d_in[17];
  const float* ca_bk = (const float*)d_in[19];
  const float* ca_bv = (const float*)d_in[21];
  const float* ca_bo = (const float*)d_in[23];
  const float* ff_W1 = (const float*)d_in[24];
  const float* ff_b1 = (const float*)d_in[25];
  const float* ff_W2 = (const float*)d_in[26];
  const float* ff_b2 = (const float*)d_in[27];
  const float* ln1_g = (const float*)d_in[28];
  const float* ln1_b = (const float*)d_in[29];
  const float* ln2_g = (const float*)d_in[30];
  const float* ln2_b = (const float*)d_in[31];
  const float* ln3_g = (const float*)d_in[32];
  const float* ln3_b = (const float*)d_in[33];
  float* out = (float*)d_out;

  // fp32 workspace
  float* ws    = (float*)d_ws;
  float* scene = ws;                       // 256
  float* x     = scene + 256;              // 32768
  float* qbuf  = x + 32768;                // 32768
  float* abuf  = qbuf + 32768;             // 32768
  float* saK   = abuf + 32768;             // 2 layers x [8][MAXS][32]
  float* saV   = saK + 2 * MAXS * DIM;
  float* memK  = saV + 2 * MAXS * DIM;     // 2 layers x [8][1024][32]
  float* memV  = memK + 2 * MEM_LEN * DIM;
  float* peA   = memV + 2 * MEM_LEN * DIM; // 32768
  float* peT   = peA + 32768;              // 3072
  // bf16 weights
  unsigned short* dxdb  = (unsigned short*)(peT + 3072); // 8 x [2][256][256]
  unsigned short* ffW1b = dxdb + 8 * 131072;             // [2][1024][256]
  unsigned short* ffW2b = ffW1b + 524288;                // [2][256][1024]
  unsigned short* inWb  = ffW2b + 524288;                // [256][160]

  const dim3 blk(256);
  const dim3 ablk(64);
  const dim3 agrid(AGENTS, NHEADS);

  // prologue
  cvt8_k<<<dim3(512, 1, 8), blk, 0, stream>>>(
      (const float*)d_in[8], (const float*)d_in[10], (const float*)d_in[12],
      (const float*)d_in[14], (const float*)d_in[16], (const float*)d_in[18],
      (const float*)d_in[20], (const float*)d_in[22], dxdb);
  cvtff_k<<<dim3(2048, 1, 2), blk, 0, stream>>>(ff_W1, ff_W2, ffW1b);
  cvtinw_k<<<160, blk, 0, stream>>>(in_W, inWb);
  pe_k<<<140, blk, 0, stream>>>(peA, peT);
  memkv_k<<<dim3(64, 1, 4), blk, 0, stream>>>(memory, dxdb, ca_bk, ca_bv, memK, memV);
  hipMemcpyAsync(scene, last_pos, 256 * sizeof(float), hipMemcpyDeviceToDevice, stream);

  for (int s = 0; s < PRED; ++s) {
    // embed + SA-QKV (layer 0)
    embed_k<<<8, blk, 0, stream>>>(scene, decoder_state, inWb, in_b, peA, peT, x, s,
        dxdb + 0 * 131072, sa_bq, qbuf,
        dxdb + 1 * 131072, sa_bk, saK + s * AGENTS * 32,
        dxdb + 2 * 131072, sa_bv, saV + s * AGENTS * 32, MAXS);

    for (int l = 0; l < 2; ++l) {
      const unsigned short* saWo = dxdb + 3 * 131072 + l * 65536;
      const unsigned short* caWq = dxdb + 4 * 131072 + l * 65536;
      const unsigned short* caWo = dxdb + 7 * 131072 + l * 65536;

      attn_k<<<agrid, ablk, 0, stream>>>(qbuf, saK + l * MAXS * DIM,
                                         saV + l * MAXS * DIM, agent_mask, abuf,
                                         (s + 1) * AGENTS, MAXS);
      oln_k<<<8, blk, 0, stream>>>(abuf, saWo, sa_bo + l * 256, x,
                                   ln1_g + l * 256, ln1_b + l * 256, x,
                                   caWq, ca_bq + l * 256, qbuf);
      attn_k<<<agrid, ablk, 0, stream>>>(qbuf, memK + l * MEM_LEN * DIM,
                                         memV + l * MEM_LEN * DIM, agent_mask, abuf,
                                         MEM_LEN, MEM_LEN);
      if (l == 0) {
        // FFN + QKV for layer 1
        ffn_k<true, false><<<8, blk, 0, stream>>>(
            abuf, caWo, ca_bo, x, ln2_g, ln2_b,
            ffW1b, ff_b1, ffW2b, ff_b2, ln3_g, ln3_b, x,
            dxdb + 0 * 131072 + 65536, sa_bq + 256, qbuf,
            dxdb + 1 * 131072 + 65536, sa_bk + 256, saK + MAXS * DIM + s * AGENTS * 32,
            dxdb + 2 * 131072 + 65536, sa_bv + 256, saV + MAXS * DIM + s * AGENTS * 32,
            MAXS,
            nullptr, nullptr, nullptr, nullptr, 0);
      } else {
        // FFN + final out-projection + scene update
        ffn_k<false, true><<<8, blk, 0, stream>>>(
            abuf, caWo, ca_bo + 256, x, ln2_g + 256, ln2_b + 256,
            ffW1b + 262144, ff_b1 + 1024, ffW2b + 262144, ff_b2 + 256,
            ln3_g + 256, ln3_b + 256, x,
            nullptr, nullptr, nullptr,
            nullptr, nullptr, nullptr,
            nullptr, nullptr, nullptr,
            MAXS,
            out_W, out_b, out, scene, s);
      }
    }
  }
}

// Round 4
// 2954.637 us; speedup vs baseline: 1.4509x; 1.4509x over previous
//
#include <hip/hip_runtime.h>
#include <math.h>

#define AGENTS 128
#define DIM 256
#define NHEADS 8
#define MEM_LEN 1024
#define MLP_DIM 1024
#define PRED 12
#define MAXS (PRED * AGENTS)   // 1536

typedef __attribute__((ext_vector_type(8))) short short8;
typedef __attribute__((ext_vector_type(4))) float f32x4;

#define MFMA(a, b, c) __builtin_amdgcn_mfma_f32_16x16x32_bf16(a, b, c, 0, 0, 0)

__device__ __forceinline__ unsigned short f2bf(float f) {
  union { float f; unsigned u; } v; v.f = f;
  unsigned r = v.u + 0x7fffu + ((v.u >> 16) & 1u);   // RNE
  return (unsigned short)(r >> 16);
}
__device__ __forceinline__ float bf2f(unsigned short s) {
  union { unsigned u; float f; } v; v.u = (unsigned)s << 16;
  return v.f;
}

// pack 8 consecutive fp32 -> bf16 frag (global or LDS)
__device__ __forceinline__ short8 afrag8(const float* p) {
  float4 a = *(const float4*)p;
  float4 b = *(const float4*)(p + 4);
  short8 r;
  r[0] = (short)f2bf(a.x); r[1] = (short)f2bf(a.y);
  r[2] = (short)f2bf(a.z); r[3] = (short)f2bf(a.w);
  r[4] = (short)f2bf(b.x); r[5] = (short)f2bf(b.y);
  r[6] = (short)f2bf(b.z); r[7] = (short)f2bf(b.w);
  return r;
}

// LayerNorm of 16 rows resident in sx; optionally mirror to global.
__device__ __forceinline__ void ln16(float (*sx)[264], const float* __restrict__ g,
                                     const float* __restrict__ b, int w, int l,
                                     float* __restrict__ gout, int row0)
{
#pragma unroll
  for (int rr = 0; rr < 4; ++rr) {
    int row = w * 4 + rr;
    float4 v = *(const float4*)&sx[row][l * 4];
    float s = v.x + v.y + v.z + v.w;
#pragma unroll
    for (int o = 32; o > 0; o >>= 1) s += __shfl_xor(s, o, 64);
    float mean = s * (1.0f / 256.0f);
    float dx = v.x - mean, dy = v.y - mean, dz = v.z - mean, dw = v.w - mean;
    float s2 = dx * dx + dy * dy + dz * dz + dw * dw;
#pragma unroll
    for (int o = 32; o > 0; o >>= 1) s2 += __shfl_xor(s2, o, 64);
    float rstd = rsqrtf(s2 * (1.0f / 256.0f) + 1e-5f);
    float4 gg = *(const float4*)&g[l * 4];
    float4 bb = *(const float4*)&b[l * 4];
    float4 o4 = make_float4(dx * rstd * gg.x + bb.x, dy * rstd * gg.y + bb.y,
                            dz * rstd * gg.z + bb.z, dw * rstd * gg.w + bb.w);
    *(float4*)&sx[row][l * 4] = o4;
    if (gout) *(float4*)&gout[(row0 + row) * DIM + l * 4] = o4;
  }
}

// 16 rows x 256 cols projection from cached A-frags; fp32 row-major out.
__device__ __forceinline__ void proj_row(
    const short8 afr[8], const unsigned short* __restrict__ W,
    const float* __restrict__ b, float* __restrict__ o, int row0, int w, int l)
{
  const int c15 = l & 15, r0 = (l >> 4) * 4;
  const int kl8 = (l >> 4) * 8;
  f32x4 acc[4] = {};
  const unsigned short* wp = W + (w * 64 + c15) * 256 + kl8;
#pragma unroll
  for (int kc = 0; kc < 8; ++kc)
#pragma unroll
    for (int t = 0; t < 4; ++t)
      acc[t] = MFMA(afr[kc], *(const short8*)(wp + t * 16 * 256 + kc * 32), acc[t]);
#pragma unroll
  for (int t = 0; t < 4; ++t) {
    int c = w * 64 + t * 16 + c15;
    float bb = b[c];
#pragma unroll
    for (int r = 0; r < 4; ++r)
      o[(row0 + r0 + r) * DIM + c] = acc[t][r] + bb;
  }
}

// K+V projections -> bf16 attention cache layouts.
// K: [h][Spad][32] key-major; V: [c][Spad] dim-major (c = h*32+d).
__device__ __forceinline__ void projKV(
    const short8 afr[8],
    const unsigned short* __restrict__ Wk, const float* __restrict__ bk,
    unsigned short* __restrict__ Ko,
    const unsigned short* __restrict__ Wv, const float* __restrict__ bv,
    unsigned short* __restrict__ Vo,
    int Spad, int crow, int w, int l)
{
  const int c15 = l & 15, r0 = (l >> 4) * 4;
  const int kl8 = (l >> 4) * 8;
  f32x4 acck[4] = {}, accv[4] = {};
  const unsigned short* wpk = Wk + (w * 64 + c15) * 256 + kl8;
  const unsigned short* wpv = Wv + (w * 64 + c15) * 256 + kl8;
#pragma unroll
  for (int kc = 0; kc < 8; ++kc)
#pragma unroll
    for (int t = 0; t < 4; ++t) {
      acck[t] = MFMA(afr[kc], *(const short8*)(wpk + t * 16 * 256 + kc * 32), acck[t]);
      accv[t] = MFMA(afr[kc], *(const short8*)(wpv + t * 16 * 256 + kc * 32), accv[t]);
    }
#pragma unroll
  for (int t = 0; t < 4; ++t) {
    int c = w * 64 + t * 16 + c15;
    int h = c >> 5, d = c & 31;
    float bbk = bk[c], bbv = bv[c];
#pragma unroll
    for (int r = 0; r < 4; ++r) {
      int row = crow + r0 + r;
      Ko[h * Spad * 32 + row * 32 + d] = f2bf(acck[t][r] + bbk);
      Vo[c * Spad + row] = f2bf(accv[t][r] + bbv);
    }
  }
}

// ---------------------------------------------------------------------------
// Embed + fused layer0 SA-QKV. Grid (8).
// ---------------------------------------------------------------------------
__global__ __launch_bounds__(256) void embed_k(
    const float* __restrict__ scene, const float* __restrict__ ds,
    const unsigned short* __restrict__ inWb, const float* __restrict__ inb,
    const float* __restrict__ peA, const float* __restrict__ peT,
    float* __restrict__ x, int step,
    const unsigned short* __restrict__ Wq, const float* __restrict__ bq, float* __restrict__ qout,
    const unsigned short* __restrict__ Wk, const float* __restrict__ bk, unsigned short* __restrict__ kout,
    const unsigned short* __restrict__ Wv, const float* __restrict__ bv, unsigned short* __restrict__ vout,
    int cbase)
{
  __shared__ float sx[16][264];
  const int tid = threadIdx.x, l = tid & 63, w = tid >> 6;
  const int c15 = l & 15, kl8 = (l >> 4) * 8, r0 = (l >> 4) * 4;
  const int row0 = blockIdx.x * 16;
  const int mrow = row0 + c15;
  f32x4 acc[4] = {};
  for (int k0 = 0; k0 < 160; k0 += 32) {
    short8 af;
#pragma unroll
    for (int j = 0; j < 8; ++j) {
      int kk = k0 + kl8 + j;
      float v = (kk < 2) ? scene[mrow * 2 + kk]
                         : ((kk < 130) ? ds[mrow * 128 + (kk - 2)] : 0.f);
      af[j] = (short)f2bf(v);
    }
    const unsigned short* wp = inWb + (w * 64 + c15) * 160 + k0 + kl8;
#pragma unroll
    for (int t = 0; t < 4; ++t)
      acc[t] = MFMA(af, *(const short8*)(wp + t * 16 * 160), acc[t]);
  }
#pragma unroll
  for (int t = 0; t < 4; ++t) {
    int c = w * 64 + t * 16 + c15;
    float bb = inb[c] + peT[step * DIM + c];
#pragma unroll
    for (int r = 0; r < 4; ++r) {
      int row = row0 + r0 + r;
      float v = acc[t][r] + bb + peA[row * DIM + c];
      sx[r0 + r][c] = v;
      x[row * DIM + c] = v;
    }
  }
  __syncthreads();
  short8 afr[8];
#pragma unroll
  for (int kc = 0; kc < 8; ++kc) afr[kc] = afrag8(&sx[c15][kc * 32 + kl8]);
  proj_row(afr, Wq, bq, qout, row0, w, l);
  projKV(afr, Wk, bk, kout, Wv, bv, vout, MAXS, cbase + row0, w, l);
}

// ---------------------------------------------------------------------------
// MFMA flash attention (no-max online softmax; scores are O(1) here).
// Grid (2, NHEADS), 256 thr = 4 waves x 16 queries.
// K bf16 [h][Spad][32]; V bf16 [c][Spad]; Q fp32 row-major; O fp32 row-major.
// ---------------------------------------------------------------------------
__global__ __launch_bounds__(256) void attn_k(
    const float* __restrict__ Q, const unsigned short* __restrict__ Kc,
    const unsigned short* __restrict__ Vt, const float* __restrict__ mask,
    float* __restrict__ O, int S, int Spad)
{
  __shared__ unsigned short pQ[4][16][80];
  const int tid = threadIdx.x, w = tid >> 6, l = tid & 63;
  const int qg = l & 15, g = l >> 4;
  const int h = blockIdx.y;
  const int qi = blockIdx.x * 64 + w * 16 + qg;   // global query row

  // Q B-frag: lane holds Q[qi][h*32 + g*8 .. +8]
  short8 qf = afrag8(Q + qi * DIM + h * 32 + g * 8);

  // mask addends for key = p*64 + t*16 + g*4 + r (period-128 tiling)
  float mk[2][4][4];
#pragma unroll
  for (int p = 0; p < 2; ++p)
#pragma unroll
    for (int t = 0; t < 4; ++t)
#pragma unroll
      for (int r = 0; r < 4; ++r)
        mk[p][t][r] = mask[qi * AGENTS + p * 64 + t * 16 + g * 4 + r];

  const unsigned short* kh = Kc + h * Spad * 32;
  const unsigned short* vh = Vt + h * 32 * Spad;
  unsigned short* pq = &pQ[w][0][0];
  const float scale = 0.17677669529663687f;  // 1/sqrt(32)
  f32x4 oa0 = {}, oa1 = {};
  float lsum = 0.f;

  for (int kc = 0; kc < S; kc += 64) {
    const int p = (kc >> 6) & 1;
    // scores^T = K.Q^T : 4 tiles of 16 keys
#pragma unroll
    for (int t = 0; t < 4; ++t) {
      short8 kf = *(const short8*)(kh + (kc + t * 16 + qg) * 32 + g * 8);
      f32x4 zz = {};
      f32x4 sc = MFMA(kf, qf, zz);
      unsigned pk0, pk1;
      {
        float e0 = __expf(sc[0] * scale + mk[p][t][0]);
        float e1 = __expf(sc[1] * scale + mk[p][t][1]);
        float e2 = __expf(sc[2] * scale + mk[p][t][2]);
        float e3 = __expf(sc[3] * scale + mk[p][t][3]);
        unsigned short b0 = f2bf(e0), b1 = f2bf(e1), b2 = f2bf(e2), b3 = f2bf(e3);
        lsum += bf2f(b0) + bf2f(b1) + bf2f(b2) + bf2f(b3);
        pk0 = (unsigned)b0 | ((unsigned)b1 << 16);
        pk1 = (unsigned)b2 | ((unsigned)b3 << 16);
      }
      uint2 u2; u2.x = pk0; u2.y = pk1;
      *(uint2*)&pq[qg * 80 + t * 16 + g * 4] = u2;   // keys t*16+g*4..+4 for query qg
    }
    // PV: O^T += V^T . P^T, 2 k-steps x 2 d-tiles
#pragma unroll
    for (int ks = 0; ks < 2; ++ks) {
      short8 pf = *(const short8*)&pq[qg * 80 + ks * 32 + g * 8];
      short8 v0 = *(const short8*)(vh + (0 * 16 + qg) * Spad + kc + ks * 32 + g * 8);
      short8 v1 = *(const short8*)(vh + (1 * 16 + qg) * Spad + kc + ks * 32 + g * 8);
      oa0 = MFMA(v0, pf, oa0);
      oa1 = MFMA(v1, pf, oa1);
    }
  }
  lsum += __shfl_xor(lsum, 16, 64);
  lsum += __shfl_xor(lsum, 32, 64);
  const float inv = 1.0f / lsum;
#pragma unroll
  for (int r = 0; r < 4; ++r) {
    O[qi * DIM + h * 32 + g * 4 + r] = oa0[r] * inv;
    O[qi * DIM + h * 32 + 16 + g * 4 + r] = oa1[r] * inv;
  }
}

// ---------------------------------------------------------------------------
// SA out-proj + LN1 + fused CA-Q projection. Grid (8).
// ---------------------------------------------------------------------------
__global__ __launch_bounds__(256) void oln_k(
    const float* __restrict__ Ain, const unsigned short* __restrict__ Wo,
    const float* __restrict__ bo, const float* __restrict__ resid,
    const float* __restrict__ g, const float* __restrict__ bv,
    float* __restrict__ xout,
    const unsigned short* __restrict__ Wq, const float* __restrict__ bq,
    float* __restrict__ qout)
{
  __shared__ float sx[16][264];
  const int tid = threadIdx.x, l = tid & 63, w = tid >> 6;
  const int c15 = l & 15, kl8 = (l >> 4) * 8, r0 = (l >> 4) * 4;
  const int row0 = blockIdx.x * 16;
  f32x4 acc[4] = {};
  const float* arow = Ain + (row0 + c15) * 256 + kl8;
  const unsigned short* wp = Wo + (w * 64 + c15) * 256 + kl8;
  for (int k0 = 0; k0 < 256; k0 += 32) {
    short8 af = afrag8(arow + k0);
#pragma unroll
    for (int t = 0; t < 4; ++t)
      acc[t] = MFMA(af, *(const short8*)(wp + t * 16 * 256 + k0), acc[t]);
  }
#pragma unroll
  for (int t = 0; t < 4; ++t) {
    int c = w * 64 + t * 16 + c15;
    float bb = bo[c];
#pragma unroll
    for (int r = 0; r < 4; ++r)
      sx[r0 + r][c] = acc[t][r] + bb + resid[(row0 + r0 + r) * DIM + c];
  }
  __syncthreads();
  ln16(sx, g, bv, w, l, xout, row0);
  __syncthreads();
  short8 afr[8];
#pragma unroll
  for (int kc = 0; kc < 8; ++kc) afr[kc] = afrag8(&sx[c15][kc * 32 + kl8]);
  proj_row(afr, Wq, bq, qout, row0, w, l);
}

// ---------------------------------------------------------------------------
// Fused: CA out-proj + LN2 + FF1(relu) + FF2 + LN3 [+ QKV(l+1) | + out-proj].
// Grid (8).
// ---------------------------------------------------------------------------
template <bool QKV, bool OUTP>
__global__ __launch_bounds__(256) void ffn_k(
    const float* __restrict__ Ain, const unsigned short* __restrict__ Wo,
    const float* __restrict__ bo, const float* __restrict__ resid,
    const float* __restrict__ g2, const float* __restrict__ b2v,
    const unsigned short* __restrict__ W1, const float* __restrict__ b1v,
    const unsigned short* __restrict__ W2, const float* __restrict__ b2f,
    const float* __restrict__ g3, const float* __restrict__ b3v,
    float* __restrict__ xout,
    const unsigned short* __restrict__ Wq, const float* __restrict__ bq, float* __restrict__ qout,
    const unsigned short* __restrict__ Wk, const float* __restrict__ bk, unsigned short* __restrict__ kout,
    const unsigned short* __restrict__ Wv, const float* __restrict__ bv, unsigned short* __restrict__ vout,
    int cbase,
    const float* __restrict__ outW, const float* __restrict__ outB,
    float* __restrict__ outbuf, float* __restrict__ scene, int step)
{
  __shared__ float sx[16][264];
  __shared__ unsigned short smid[16][1032];
  const int tid = threadIdx.x, l = tid & 63, w = tid >> 6;
  const int c15 = l & 15, kl8 = (l >> 4) * 8, r0 = (l >> 4) * 4;
  const int row0 = blockIdx.x * 16;

  // A: CA out-proj + bias + residual -> sx
  {
    f32x4 acc[4] = {};
    const float* arow = Ain + (row0 + c15) * 256 + kl8;
    const unsigned short* wp = Wo + (w * 64 + c15) * 256 + kl8;
    for (int k0 = 0; k0 < 256; k0 += 32) {
      short8 af = afrag8(arow + k0);
#pragma unroll
      for (int t = 0; t < 4; ++t)
        acc[t] = MFMA(af, *(const short8*)(wp + t * 16 * 256 + k0), acc[t]);
    }
#pragma unroll
    for (int t = 0; t < 4; ++t) {
      int c = w * 64 + t * 16 + c15;
      float bb = bo[c];
#pragma unroll
      for (int r = 0; r < 4; ++r)
        sx[r0 + r][c] = acc[t][r] + bb + resid[(row0 + r0 + r) * DIM + c];
    }
  }
  __syncthreads();
  ln16(sx, g2, b2v, w, l, nullptr, row0);
  __syncthreads();
  // C: FF1 + relu -> smid (bf16). Wave w owns cols [w*256, w*256+256).
  {
    short8 afr[8];
#pragma unroll
    for (int kc = 0; kc < 8; ++kc) afr[kc] = afrag8(&sx[c15][kc * 32 + kl8]);
#pragma unroll 4
    for (int t = 0; t < 16; ++t) {
      f32x4 acc = {};
      const unsigned short* wp = W1 + (w * 256 + t * 16 + c15) * 256 + kl8;
#pragma unroll
      for (int kc = 0; kc < 8; ++kc)
        acc = MFMA(afr[kc], *(const short8*)(wp + kc * 32), acc);
      int c = w * 256 + t * 16 + c15;
      float bb = b1v[c];
#pragma unroll
      for (int r = 0; r < 4; ++r)
        smid[r0 + r][c] = f2bf(fmaxf(acc[r] + bb, 0.f));
    }
  }
  __syncthreads();
  // D: FF2 (K=1024) from smid
  f32x4 facc[4] = {};
  for (int kc = 0; kc < 4; ++kc) {
    short8 afr[8];
#pragma unroll
    for (int kk = 0; kk < 8; ++kk)
      afr[kk] = *(const short8*)&smid[c15][kc * 256 + kk * 32 + kl8];
    const unsigned short* wp = W2 + (w * 64 + c15) * 1024 + kc * 256 + kl8;
#pragma unroll
    for (int t = 0; t < 4; ++t)
#pragma unroll
      for (int kk = 0; kk < 8; ++kk)
        facc[t] = MFMA(afr[kk], *(const short8*)(wp + t * 16 * 1024 + kk * 32), facc[t]);
  }
#pragma unroll
  for (int t = 0; t < 4; ++t) {
    int c = w * 64 + t * 16 + c15;
    float bb = b2f[c];
#pragma unroll
    for (int r = 0; r < 4; ++r)
      sx[r0 + r][c] = facc[t][r] + bb + sx[r0 + r][c];
  }
  __syncthreads();
  ln16(sx, g3, b3v, w, l, xout, row0);
  __syncthreads();
  if (QKV) {
    short8 afr[8];
#pragma unroll
    for (int kc = 0; kc < 8; ++kc) afr[kc] = afrag8(&sx[c15][kc * 32 + kl8]);
    proj_row(afr, Wq, bq, qout, row0, w, l);
    projKV(afr, Wk, bk, kout, Wv, bv, vout, MAXS, cbase + row0, w, l);
  }
  if (OUTP) {
    int il = tid >> 4, jj = (tid >> 3) & 1, kc = tid & 7;
    float a = 0.f;
    const float* sxr = &sx[il][kc * 32];
    const float* wr = outW + jj * 256 + kc * 32;
#pragma unroll
    for (int k = 0; k < 32; ++k) a += sxr[k] * wr[k];
#pragma unroll
    for (int off = 4; off > 0; off >>= 1) a += __shfl_xor(a, off, 64);
    if (kc == 0) {
      a += outB[jj];
      int gi = row0 + il;
      outbuf[(step * AGENTS + gi) * 2 + jj] = a;
      scene[gi * 2 + jj] += a;
    }
  }
}

// ---------------------------------------------------------------------------
// memory K/V precompute -> bf16 cache layouts. Grid (64, 1, 2 layers).
// ---------------------------------------------------------------------------
__global__ __launch_bounds__(256) void memkv_k(
    const float* __restrict__ mem, const unsigned short* __restrict__ dxd,
    const float* __restrict__ bk, const float* __restrict__ bvv,
    unsigned short* __restrict__ memK, unsigned short* __restrict__ memV)
{
  const int li = blockIdx.z;
  const unsigned short* Wk = dxd + 5 * 131072 + li * 65536;
  const unsigned short* Wv = dxd + 6 * 131072 + li * 65536;
  const int tid = threadIdx.x, l = tid & 63, w = tid >> 6;
  const int c15 = l & 15, kl8 = (l >> 4) * 8;
  const int row0 = blockIdx.x * 16;
  short8 afr[8];
#pragma unroll
  for (int kc = 0; kc < 8; ++kc)
    afr[kc] = afrag8(mem + (row0 + c15) * 256 + kc * 32 + kl8);
  projKV(afr, Wk, bk + li * 256, memK + li * MEM_LEN * 256,
         Wv, bvv + li * 256, memV + li * MEM_LEN * 256, MEM_LEN, row0, w, l);
}

// ---------------------------------------------------------------------------
// Prologue converters / tables
// ---------------------------------------------------------------------------
__global__ void cvt8_k(const float* p0, const float* p1, const float* p2,
                       const float* p3, const float* p4, const float* p5,
                       const float* p6, const float* p7, unsigned short* dst)
{
  const float* s;
  switch (blockIdx.z) {
    case 0: s = p0; break; case 1: s = p1; break;
    case 2: s = p2; break; case 3: s = p3; break;
    case 4: s = p4; break; case 5: s = p5; break;
    case 6: s = p6; break; default: s = p7; break;
  }
  int i = blockIdx.x * 256 + threadIdx.x;
  dst[blockIdx.z * 131072 + i] = f2bf(s[i]);
}

__global__ void cvtff_k(const float* w1, const float* w2, unsigned short* dst)
{
  const float* s = blockIdx.z ? w2 : w1;
  int i = blockIdx.x * 256 + threadIdx.x;
  dst[blockIdx.z * 524288 + i] = f2bf(s[i]);
}

__global__ void cvtinw_k(const float* w, unsigned short* dst)
{
  int i = blockIdx.x * 256 + threadIdx.x;
  if (i >= 256 * 160) return;
  int n = i / 160, k = i - n * 160;
  dst[i] = (k < 130) ? f2bf(w[n * 130 + k]) : (unsigned short)0;
}

__global__ void pe_k(float* peA, float* peT)
{
  int i = blockIdx.x * 256 + threadIdx.x;
  if (i < 128 * 256) {
    int row = i >> 8, c = i & 255, p = c >> 1;
    float dv = expf((float)(2 * p) * (-9.210340371976184f / 256.f));
    float ang = (float)row * dv;
    peA[i] = (c & 1) ? cosf(ang) : sinf(ang);
  } else if (i < 140 * 256) {
    int j = i - 32768;
    int s = j >> 8, c = j & 255, p = c >> 1;
    float dv = expf((float)(2 * p) * (-9.210340371976184f / 256.f));
    float ang = (float)s * dv;
    peT[j] = (c & 1) ? cosf(ang) : sinf(ang);
  }
}

// ---------------------------------------------------------------------------
extern "C" void kernel_launch(void* const* d_in, const int* in_sizes, int n_in,
                              void* d_out, int out_size, void* d_ws, size_t ws_size,
                              hipStream_t stream)
{
  const float* last_pos      = (const float*)d_in[0];
  const float* decoder_state = (const float*)d_in[1];
  const float* memory        = (const float*)d_in[2];
  const float* agent_mask    = (const float*)d_in[3];
  const float* in_W  = (const float*)d_in[4];
  const float* in_b  = (const float*)d_in[5];
  const float* out_W = (const float*)d_in[6];
  const float* out_b = (const float*)d_in[7];
  const float* sa_bq = (const float*)d_in[9];
  const float* sa_bk = (const float*)d_in[11];
  const float* sa_bv = (const float*)d_in[13];
  const float* sa_bo = (const float*)d_in[15];
  const float* ca_bq = (const float*)d_in[17];
  const float* ca_bk = (const float*)d_in[19];
  const float* ca_bv = (const float*)d_in[21];
  const float* ca_bo = (const float*)d_in[23];
  const float* ff_W1 = (const float*)d_in[24];
  const float* ff_b1 = (const float*)d_in[25];
  const float* ff_W2 = (const float*)d_in[26];
  const float* ff_b2 = (const float*)d_in[27];
  const float* ln1_g = (const float*)d_in[28];
  const float* ln1_b = (const float*)d_in[29];
  const float* ln2_g = (const float*)d_in[30];
  const float* ln2_b = (const float*)d_in[31];
  const float* ln3_g = (const float*)d_in[32];
  const float* ln3_b = (const float*)d_in[33];
  float* out = (float*)d_out;

  // workspace
  float* ws    = (float*)d_ws;
  float* scene = ws;                       // 256
  float* x     = scene + 256;              // 32768
  float* qbuf  = x + 32768;                // 32768
  float* abuf  = qbuf + 32768;             // 32768
  float* peA   = abuf + 32768;             // 32768
  float* peT   = peA + 32768;              // 3072
  unsigned short* saK  = (unsigned short*)(peT + 3072);  // 2 x [8][1536][32]
  unsigned short* saV  = saK + 2 * MAXS * 256;            // 2 x [256][1536]
  unsigned short* memK = saV + 2 * MAXS * 256;            // 2 x [8][1024][32]
  unsigned short* memV = memK + 2 * MEM_LEN * 256;        // 2 x [256][1024]
  unsigned short* dxdb  = memV + 2 * MEM_LEN * 256;       // 8 x [2][256][256]
  unsigned short* ffW1b = dxdb + 8 * 131072;
  unsigned short* ffW2b = ffW1b + 524288;
  unsigned short* inWb  = ffW2b + 524288;

  const dim3 blk(256);
  const dim3 agrid(2, NHEADS);

  // prologue
  cvt8_k<<<dim3(512, 1, 8), blk, 0, stream>>>(
      (const float*)d_in[8], (const float*)d_in[10], (const float*)d_in[12],
      (const float*)d_in[14], (const float*)d_in[16], (const float*)d_in[18],
      (const float*)d_in[20], (const float*)d_in[22], dxdb);
  cvtff_k<<<dim3(2048, 1, 2), blk, 0, stream>>>(ff_W1, ff_W2, ffW1b);
  cvtinw_k<<<160, blk, 0, stream>>>(in_W, inWb);
  pe_k<<<140, blk, 0, stream>>>(peA, peT);
  memkv_k<<<dim3(64, 1, 2), blk, 0, stream>>>(memory, dxdb, ca_bk, ca_bv, memK, memV);
  hipMemcpyAsync(scene, last_pos, 256 * sizeof(float), hipMemcpyDeviceToDevice, stream);

  for (int s = 0; s < PRED; ++s) {
    embed_k<<<8, blk, 0, stream>>>(scene, decoder_state, inWb, in_b, peA, peT, x, s,
        dxdb + 0 * 131072, sa_bq, qbuf,
        dxdb + 1 * 131072, sa_bk, saK,
        dxdb + 2 * 131072, sa_bv, saV, s * AGENTS);

    for (int l = 0; l < 2; ++l) {
      const unsigned short* saWo = dxdb + 3 * 131072 + l * 65536;
      const unsigned short* caWq = dxdb + 4 * 131072 + l * 65536;
      const unsigned short* caWo = dxdb + 7 * 131072 + l * 65536;

      attn_k<<<agrid, blk, 0, stream>>>(qbuf, saK + l * MAXS * 256,
                                        saV + l * MAXS * 256, agent_mask, abuf,
                                        (s + 1) * AGENTS, MAXS);
      oln_k<<<8, blk, 0, stream>>>(abuf, saWo, sa_bo + l * 256, x,
                                   ln1_g + l * 256, ln1_b + l * 256, x,
                                   caWq, ca_bq + l * 256, qbuf);
      attn_k<<<agrid, blk, 0, stream>>>(qbuf, memK + l * MEM_LEN * 256,
                                        memV + l * MEM_LEN * 256, agent_mask, abuf,
                                        MEM_LEN, MEM_LEN);
      if (l == 0) {
        ffn_k<true, false><<<8, blk, 0, stream>>>(
            abuf, caWo, ca_bo, x, ln2_g, ln2_b,
            ffW1b, ff_b1, ffW2b, ff_b2, ln3_g, ln3_b, x,
            dxdb + 0 * 131072 + 65536, sa_bq + 256, qbuf,
            dxdb + 1 * 131072 + 65536, sa_bk + 256, saK + MAXS * 256,
            dxdb + 2 * 131072 + 65536, sa_bv + 256, saV + MAXS * 256,
            s * AGENTS,
            nullptr, nullptr, nullptr, nullptr, 0);
      } else {
        ffn_k<false, true><<<8, blk, 0, stream>>>(
            abuf, caWo, ca_bo + 256, x, ln2_g + 256, ln2_b + 256,
            ffW1b + 262144, ff_b1 + 1024, ffW2b + 262144, ff_b2 + 256,
            ln3_g + 256, ln3_b + 256, x,
            nullptr, nullptr, nullptr,
            nullptr, nullptr, nullptr,
            nullptr, nullptr, nullptr,
            0,
            out_W, out_b, out, scene, s);
      }
    }
  }
}

// Round 5
// 2481.293 us; speedup vs baseline: 1.7277x; 1.1908x over previous
//
#include <hip/hip_runtime.h>
#include <math.h>

#define AGENTS 128
#define DIM 256
#define NHEADS 8
#define MEM_LEN 1024
#define MLP_DIM 1024
#define PRED 12
#define MAXS (PRED * AGENTS)   // 1536

typedef __attribute__((ext_vector_type(8))) short short8;
typedef __attribute__((ext_vector_type(4))) float f32x4;

#define MFMA(a, b, c) __builtin_amdgcn_mfma_f32_16x16x32_bf16(a, b, c, 0, 0, 0)

__device__ __forceinline__ unsigned short f2bf(float f) {
  union { float f; unsigned u; } v; v.f = f;
  unsigned r = v.u + 0x7fffu + ((v.u >> 16) & 1u);   // RNE
  return (unsigned short)(r >> 16);
}

// pack 8 consecutive fp32 -> bf16 frag
__device__ __forceinline__ short8 afrag8(const float* p) {
  float4 a = *(const float4*)p;
  float4 b = *(const float4*)(p + 4);
  short8 r;
  r[0] = (short)f2bf(a.x); r[1] = (short)f2bf(a.y);
  r[2] = (short)f2bf(a.z); r[3] = (short)f2bf(a.w);
  r[4] = (short)f2bf(b.x); r[5] = (short)f2bf(b.y);
  r[6] = (short)f2bf(b.z); r[7] = (short)f2bf(b.w);
  return r;
}

// finalize per-row LN stats from 4 col-block partials: pst[row][cb] = (sum, sumsq)
__device__ __forceinline__ void ln_stats(const float* __restrict__ pst, int row,
                                         float& mean, float& rstd) {
  float4 p0 = *(const float4*)(pst + row * 8);
  float4 p1 = *(const float4*)(pst + row * 8 + 4);
  float s  = p0.x + p0.z + p1.x + p1.z;
  float ss = p0.y + p0.w + p1.y + p1.w;
  mean = s * (1.0f / 256.0f);
  rstd = rsqrtf(ss * (1.0f / 256.0f) - mean * mean + 1e-5f);
}

// A-frag with on-the-fly LayerNorm: 8 elems at Y[row][k..k+8)
__device__ __forceinline__ short8 afragLN(const float* __restrict__ yr,
                                          const float* __restrict__ lg,
                                          const float* __restrict__ lb,
                                          int k, float mean, float rstd) {
  float4 a = *(const float4*)(yr + k), b = *(const float4*)(yr + k + 4);
  float4 ga = *(const float4*)(lg + k), gb = *(const float4*)(lg + k + 4);
  float4 ba = *(const float4*)(lb + k), bb = *(const float4*)(lb + k + 4);
  short8 r;
  r[0] = (short)f2bf((a.x - mean) * rstd * ga.x + ba.x);
  r[1] = (short)f2bf((a.y - mean) * rstd * ga.y + ba.y);
  r[2] = (short)f2bf((a.z - mean) * rstd * ga.z + ba.z);
  r[3] = (short)f2bf((a.w - mean) * rstd * ga.w + ba.w);
  r[4] = (short)f2bf((b.x - mean) * rstd * gb.x + bb.x);
  r[5] = (short)f2bf((b.y - mean) * rstd * gb.y + bb.y);
  r[6] = (short)f2bf((b.z - mean) * rstd * gb.z + bb.z);
  r[7] = (short)f2bf((b.w - mean) * rstd * gb.w + bb.w);
  return r;
}

// ---------------------------------------------------------------------------
// Wide projection GEMM. Block = 64 rows x 64 cols, 4 waves (wave w = 16 rows).
// Grid (Mrows/64, Ncols/64). AMODE: 0 = bf16 A (ab, lda); 1 = fp32 Y + LN.
// RES: 0 none; 1 plain fp32 resid; 2 LN(Yp, pstp, gp, bp).
// EPI: 0 = write Yo fp32 [*,256] + partial stats psto; 1 = relu->bf16 mido [*,1024].
// ---------------------------------------------------------------------------
template <int AMODE, int RES, int EPI>
__global__ __launch_bounds__(256) void wproj_k(
    const unsigned short* __restrict__ ab, int lda,
    const float* __restrict__ Ya, const float* __restrict__ psta,
    const float* __restrict__ lga, const float* __restrict__ lba,
    const unsigned short* __restrict__ W, const float* __restrict__ bias, int K,
    const float* __restrict__ res,
    const float* __restrict__ Yp, const float* __restrict__ pstp,
    const float* __restrict__ gp, const float* __restrict__ bp,
    float* __restrict__ Yo, float* __restrict__ psto,
    unsigned short* __restrict__ mido)
{
  const int tid = threadIdx.x, l = tid & 63, w = tid >> 6;
  const int c15 = l & 15, g8 = (l >> 4) * 8, r0v = (l >> 4) * 4;
  const int rowb = blockIdx.x * 64 + w * 16;
  const int arow = rowb + c15;
  const int cb = blockIdx.y;
  const int colb = cb * 64;

  float meanA = 0.f, rstdA = 0.f;
  if (AMODE == 1) ln_stats(psta, arow, meanA, rstdA);

  const int KC = K >> 5;
  f32x4 acc[4] = {};
  const unsigned short* wp = W + (colb + c15) * K + g8;
  for (int kc = 0; kc < KC; ++kc) {
    short8 af;
    if (AMODE == 0) af = *(const short8*)(ab + arow * lda + kc * 32 + g8);
    else af = afragLN(Ya + arow * 256, lga, lba, kc * 32 + g8, meanA, rstdA);
#pragma unroll
    for (int t = 0; t < 4; ++t)
      acc[t] = MFMA(af, *(const short8*)(wp + t * 16 * K + kc * 32), acc[t]);
  }

  float mp[4], rp[4];
  if (RES == 2) {
#pragma unroll
    for (int r = 0; r < 4; ++r) ln_stats(pstp, rowb + r0v + r, mp[r], rp[r]);
  }

  float v[4][4];
#pragma unroll
  for (int t = 0; t < 4; ++t) {
    const int col = colb + t * 16 + c15;
    const float bb = bias[col];
    float gpp = 0.f, bpp = 0.f;
    if (RES == 2) { gpp = gp[col]; bpp = bp[col]; }
#pragma unroll
    for (int r = 0; r < 4; ++r) {
      const int row = rowb + r0v + r;
      float x = acc[t][r] + bb;
      if (RES == 1) x += res[row * 256 + col];
      if (RES == 2) x += (Yp[row * 256 + col] - mp[r]) * rp[r] * gpp + bpp;
      if (EPI == 0) Yo[row * 256 + col] = x;
      if (EPI == 1) mido[row * 1024 + col] = f2bf(fmaxf(x, 0.f));
      v[t][r] = x;
    }
  }
  if (EPI == 0) {
#pragma unroll
    for (int r = 0; r < 4; ++r) {
      float s  = v[0][r] + v[1][r] + v[2][r] + v[3][r];
      float ss = v[0][r]*v[0][r] + v[1][r]*v[1][r] + v[2][r]*v[2][r] + v[3][r]*v[3][r];
#pragma unroll
      for (int m = 1; m < 16; m <<= 1) {
        s  += __shfl_xor(s, m, 64);
        ss += __shfl_xor(ss, m, 64);
      }
      if (c15 == 0) {
        const int row = rowb + r0v + r;
        psto[row * 8 + cb * 2]     = s;
        psto[row * 8 + cb * 2 + 1] = ss;
      }
    }
  }
}

// ---------------------------------------------------------------------------
// K+V projection into attention-cache layouts. Grid (M/64, 8): y<4 -> K cols
// (y&3)*64; y>=4 -> V. K: [h][Spad][32] bf16; V: [c][Spad] bf16.
// AMODE: 0 bf16 ab; 1 fp32 Y + LN; 2 plain fp32 (af32).
// ---------------------------------------------------------------------------
template <int AMODE>
__global__ __launch_bounds__(256) void kvproj_k(
    const unsigned short* __restrict__ ab, int lda,
    const float* __restrict__ Ya, const float* __restrict__ psta,
    const float* __restrict__ lga, const float* __restrict__ lba,
    const float* __restrict__ af32,
    const unsigned short* __restrict__ Wk, const float* __restrict__ bk,
    const unsigned short* __restrict__ Wv, const float* __restrict__ bv,
    unsigned short* __restrict__ Ko, unsigned short* __restrict__ Vo,
    int Spad, int crow)
{
  const int tid = threadIdx.x, l = tid & 63, w = tid >> 6;
  const int c15 = l & 15, g8 = (l >> 4) * 8, r0v = (l >> 4) * 4;
  const int rowb = blockIdx.x * 64 + w * 16;
  const int arow = rowb + c15;
  const int y = blockIdx.y;
  const bool isK = y < 4;
  const int colb = (y & 3) * 64;
  const unsigned short* W = isK ? Wk : Wv;
  const float* bias = isK ? bk : bv;

  float meanA = 0.f, rstdA = 0.f;
  if (AMODE == 1) ln_stats(psta, arow, meanA, rstdA);

  f32x4 acc[4] = {};
  const unsigned short* wp = W + (colb + c15) * 256 + g8;
  for (int kc = 0; kc < 8; ++kc) {
    short8 af;
    if (AMODE == 0) af = *(const short8*)(ab + arow * lda + kc * 32 + g8);
    else if (AMODE == 1) af = afragLN(Ya + arow * 256, lga, lba, kc * 32 + g8, meanA, rstdA);
    else af = afrag8(af32 + arow * 256 + kc * 32 + g8);
#pragma unroll
    for (int t = 0; t < 4; ++t)
      acc[t] = MFMA(af, *(const short8*)(wp + t * 16 * 256 + kc * 32), acc[t]);
  }
#pragma unroll
  for (int t = 0; t < 4; ++t) {
    const int col = colb + t * 16 + c15;
    const float bb = bias[col];
    const int hh = col >> 5, d = col & 31;
#pragma unroll
    for (int r = 0; r < 4; ++r) {
      const int row = crow + rowb + r0v + r;
      unsigned short val = f2bf(acc[t][r] + bb);
      if (isK) Ko[hh * Spad * 32 + row * 32 + d] = val;
      else     Vo[col * Spad + row] = val;
    }
  }
}

// ---------------------------------------------------------------------------
// Attention with fused Q-projection. Grid (2, NHEADS), 256 thr = 4 waves x 16 q.
// AMODE: 0 = bf16 x (ab); 1 = fp32 Y + LN. Output Ob bf16 row-major [128][256].
// ---------------------------------------------------------------------------
template <int AMODE>
__global__ __launch_bounds__(256) void attn2_k(
    const unsigned short* __restrict__ ab,
    const float* __restrict__ Ya, const float* __restrict__ psta,
    const float* __restrict__ lga, const float* __restrict__ lba,
    const unsigned short* __restrict__ Wq, const float* __restrict__ bq,
    const unsigned short* __restrict__ Kc, const unsigned short* __restrict__ Vt,
    const float* __restrict__ mask, unsigned short* __restrict__ Ob,
    int S, int Spad)
{
  __shared__ unsigned short sq[4][16][32];
  __shared__ unsigned short ps[4][16][96];
  const int tid = threadIdx.x, l = tid & 63, w = tid >> 6;
  const int c15 = l & 15, g = l >> 4, g8 = g * 8, r0v = g * 4;
  const int h = blockIdx.y;
  const int rowb = blockIdx.x * 64 + w * 16;
  const int arow = rowb + c15;

  // ---- Q projection (16 rows x 32 cols per wave) ----
  float meanA = 0.f, rstdA = 0.f;
  if (AMODE == 1) ln_stats(psta, arow, meanA, rstdA);
  f32x4 q0 = {}, q1 = {};
  const unsigned short* wp = Wq + (h * 32 + c15) * 256 + g8;
  for (int kc = 0; kc < 8; ++kc) {
    short8 af;
    if (AMODE == 0) af = *(const short8*)(ab + arow * 256 + kc * 32 + g8);
    else af = afragLN(Ya + arow * 256, lga, lba, kc * 32 + g8, meanA, rstdA);
    q0 = MFMA(af, *(const short8*)(wp + kc * 32), q0);
    q1 = MFMA(af, *(const short8*)(wp + 16 * 256 + kc * 32), q1);
  }
  {
    const float b0 = bq[h * 32 + c15], b1 = bq[h * 32 + 16 + c15];
#pragma unroll
    for (int r = 0; r < 4; ++r) {
      sq[w][r0v + r][c15]      = f2bf(q0[r] + b0);
      sq[w][r0v + r][16 + c15] = f2bf(q1[r] + b1);
    }
  }
  short8 qf = *(const short8*)&sq[w][c15][g8];   // wave-private: no barrier

  // ---- mask addends (period-128 tiling) ----
  float mk[2][4][4];
#pragma unroll
  for (int p = 0; p < 2; ++p)
#pragma unroll
    for (int t = 0; t < 4; ++t)
#pragma unroll
      for (int r = 0; r < 4; ++r)
        mk[p][t][r] = mask[arow * AGENTS + p * 64 + t * 16 + g * 4 + r];

  const unsigned short* kh = Kc + h * Spad * 32;
  const unsigned short* vh = Vt + h * 32 * Spad;
  unsigned short* pq = &ps[w][0][0];
  const float scale = 0.17677669529663687f;  // 1/sqrt(32)
  f32x4 oa0 = {}, oa1 = {};
  float lsum = 0.f;

  for (int kc = 0; kc < S; kc += 64) {
    const int p = (kc >> 6) & 1;
#pragma unroll
    for (int t = 0; t < 4; ++t) {
      short8 kf = *(const short8*)(kh + (kc + t * 16 + c15) * 32 + g8);
      f32x4 zz = {};
      f32x4 sc = MFMA(kf, qf, zz);
      float e0 = __expf(sc[0] * scale + mk[p][t][0]);
      float e1 = __expf(sc[1] * scale + mk[p][t][1]);
      float e2 = __expf(sc[2] * scale + mk[p][t][2]);
      float e3 = __expf(sc[3] * scale + mk[p][t][3]);
      unsigned short b0 = f2bf(e0), b1 = f2bf(e1), b2 = f2bf(e2), b3 = f2bf(e3);
      union { unsigned u; float f; } c0, c1, c2, c3;
      c0.u = (unsigned)b0 << 16; c1.u = (unsigned)b1 << 16;
      c2.u = (unsigned)b2 << 16; c3.u = (unsigned)b3 << 16;
      lsum += c0.f + c1.f + c2.f + c3.f;
      uint2 u2;
      u2.x = (unsigned)b0 | ((unsigned)b1 << 16);
      u2.y = (unsigned)b2 | ((unsigned)b3 << 16);
      *(uint2*)&pq[c15 * 96 + t * 16 + g * 4] = u2;
    }
#pragma unroll
    for (int ks = 0; ks < 2; ++ks) {
      short8 pf = *(const short8*)&pq[c15 * 96 + ks * 32 + g8];
      short8 v0 = *(const short8*)(vh + c15 * Spad + kc + ks * 32 + g8);
      short8 v1 = *(const short8*)(vh + (16 + c15) * Spad + kc + ks * 32 + g8);
      oa0 = MFMA(v0, pf, oa0);
      oa1 = MFMA(v1, pf, oa1);
    }
  }
  lsum += __shfl_xor(lsum, 16, 64);
  lsum += __shfl_xor(lsum, 32, 64);
  const float inv = 1.0f / lsum;
#pragma unroll
  for (int r = 0; r < 4; ++r) {
    Ob[arow * DIM + h * 32 + g * 4 + r]      = f2bf(oa0[r] * inv);
    Ob[arow * DIM + h * 32 + 16 + g * 4 + r] = f2bf(oa1[r] * inv);
  }
}

// ---------------------------------------------------------------------------
// Embed: x0 = [scene|ds] @ inW^T + inb + PE. Grid (2,4). Writes fp32 + bf16.
// ---------------------------------------------------------------------------
__global__ __launch_bounds__(256) void embed_k(
    const float* __restrict__ scene, const float* __restrict__ ds,
    const unsigned short* __restrict__ inWb, const float* __restrict__ inb,
    const float* __restrict__ peA, const float* __restrict__ peT,
    float* __restrict__ x0, unsigned short* __restrict__ xb0, int step)
{
  const int tid = threadIdx.x, l = tid & 63, w = tid >> 6;
  const int c15 = l & 15, g8 = (l >> 4) * 8, r0v = (l >> 4) * 4;
  const int rowb = blockIdx.x * 64 + w * 16;
  const int arow = rowb + c15;
  const int colb = blockIdx.y * 64;
  f32x4 acc[4] = {};
  const unsigned short* wp = inWb + (colb + c15) * 160 + g8;
  for (int kc = 0; kc < 5; ++kc) {
    short8 af;
#pragma unroll
    for (int j = 0; j < 8; ++j) {
      int kk = kc * 32 + g8 + j;
      float v = (kk < 2) ? scene[arow * 2 + kk]
                         : ((kk < 130) ? ds[arow * 128 + (kk - 2)] : 0.f);
      af[j] = (short)f2bf(v);
    }
#pragma unroll
    for (int t = 0; t < 4; ++t)
      acc[t] = MFMA(af, *(const short8*)(wp + t * 16 * 160 + kc * 32), acc[t]);
  }
#pragma unroll
  for (int t = 0; t < 4; ++t) {
    const int col = colb + t * 16 + c15;
    const float bb = inb[col] + peT[step * DIM + col];
#pragma unroll
    for (int r = 0; r < 4; ++r) {
      const int row = rowb + r0v + r;
      float v = acc[t][r] + bb + peA[row * DIM + col];
      x0[row * DIM + col] = v;
      xb0[row * DIM + col] = f2bf(v);
    }
  }
}

// ---------------------------------------------------------------------------
// Final: x3 = LN3(Y3); rel = x3 @ outW^T + ob; out[s]=rel; scene += rel.
// Grid 1, 256 thr = 128 rows x 2 cols.
// ---------------------------------------------------------------------------
__global__ __launch_bounds__(256) void outp_k(
    const float* __restrict__ Y3, const float* __restrict__ pst3,
    const float* __restrict__ g3, const float* __restrict__ b3,
    const float* __restrict__ outW, const float* __restrict__ outB,
    float* __restrict__ outbuf, float* __restrict__ scene, int step)
{
  const int tid = threadIdx.x;
  const int row = tid >> 1, j = tid & 1;
  float mean, rstd;
  ln_stats(pst3, row, mean, rstd);
  const float* yr = Y3 + row * 256;
  const float* wr = outW + j * 256;
  float a = 0.f;
  for (int k = 0; k < 256; k += 4) {
    float4 y = *(const float4*)(yr + k);
    float4 gg = *(const float4*)(g3 + k);
    float4 bb = *(const float4*)(b3 + k);
    float4 ww = *(const float4*)(wr + k);
    a += ((y.x - mean) * rstd * gg.x + bb.x) * ww.x
       + ((y.y - mean) * rstd * gg.y + bb.y) * ww.y
       + ((y.z - mean) * rstd * gg.z + bb.z) * ww.z
       + ((y.w - mean) * rstd * gg.w + bb.w) * ww.w;
  }
  a += outB[j];
  outbuf[(step * AGENTS + row) * 2 + j] = a;
  scene[row * 2 + j] += a;
}

// ---------------------------------------------------------------------------
// Prologue converters / tables
// ---------------------------------------------------------------------------
__global__ void cvt8_k(const float* p0, const float* p1, const float* p2,
                       const float* p3, const float* p4, const float* p5,
                       const float* p6, const float* p7, unsigned short* dst)
{
  const float* s;
  switch (blockIdx.z) {
    case 0: s = p0; break; case 1: s = p1; break;
    case 2: s = p2; break; case 3: s = p3; break;
    case 4: s = p4; break; case 5: s = p5; break;
    case 6: s = p6; break; default: s = p7; break;
  }
  int i = blockIdx.x * 256 + threadIdx.x;
  dst[blockIdx.z * 131072 + i] = f2bf(s[i]);
}

__global__ void cvtff_k(const float* w1, const float* w2, unsigned short* dst)
{
  const float* s = blockIdx.z ? w2 : w1;
  int i = blockIdx.x * 256 + threadIdx.x;
  dst[blockIdx.z * 524288 + i] = f2bf(s[i]);
}

__global__ void cvtinw_k(const float* w, unsigned short* dst)
{
  int i = blockIdx.x * 256 + threadIdx.x;
  if (i >= 256 * 160) return;
  int n = i / 160, k = i - n * 160;
  dst[i] = (k < 130) ? f2bf(w[n * 130 + k]) : (unsigned short)0;
}

__global__ void pe_k(float* peA, float* peT)
{
  int i = blockIdx.x * 256 + threadIdx.x;
  if (i < 128 * 256) {
    int row = i >> 8, c = i & 255, p = c >> 1;
    float dv = expf((float)(2 * p) * (-9.210340371976184f / 256.f));
    float ang = (float)row * dv;
    peA[i] = (c & 1) ? cosf(ang) : sinf(ang);
  } else if (i < 140 * 256) {
    int j = i - 32768;
    int s = j >> 8, c = j & 255, p = c >> 1;
    float dv = expf((float)(2 * p) * (-9.210340371976184f / 256.f));
    float ang = (float)s * dv;
    peT[j] = (c & 1) ? cosf(ang) : sinf(ang);
  }
}

// ---------------------------------------------------------------------------
extern "C" void kernel_launch(void* const* d_in, const int* in_sizes, int n_in,
                              void* d_out, int out_size, void* d_ws, size_t ws_size,
                              hipStream_t stream)
{
  const float* last_pos      = (const float*)d_in[0];
  const float* decoder_state = (const float*)d_in[1];
  const float* memory        = (const float*)d_in[2];
  const float* agent_mask    = (const float*)d_in[3];
  const float* in_W  = (const float*)d_in[4];
  const float* in_b  = (const float*)d_in[5];
  const float* out_W = (const float*)d_in[6];
  const float* out_b = (const float*)d_in[7];
  const float* sa_bq = (const float*)d_in[9];
  const float* sa_bk = (const float*)d_in[11];
  const float* sa_bv = (const float*)d_in[13];
  const float* sa_bo = (const float*)d_in[15];
  const float* ca_bq = (const float*)d_in[17];
  const float* ca_bk = (const float*)d_in[19];
  const float* ca_bv = (const float*)d_in[21];
  const float* ca_bo = (const float*)d_in[23];
  const float* ff_W1 = (const float*)d_in[24];
  const float* ff_b1 = (const float*)d_in[25];
  const float* ff_W2 = (const float*)d_in[26];
  const float* ff_b2 = (const float*)d_in[27];
  const float* ln1_g = (const float*)d_in[28];
  const float* ln1_b = (const float*)d_in[29];
  const float* ln2_g = (const float*)d_in[30];
  const float* ln2_b = (const float*)d_in[31];
  const float* ln3_g = (const float*)d_in[32];
  const float* ln3_b = (const float*)d_in[33];
  float* out = (float*)d_out;

  // fp32 workspace
  float* ws    = (float*)d_ws;
  float* scene = ws;               // 256
  float* x0    = scene + 256;      // 32768
  float* Y1    = x0 + 32768;       // 32768
  float* Y2    = Y1 + 32768;       // 32768
  float* Y3    = Y2 + 32768;       // 32768
  float* pst1  = Y3 + 32768;       // 1024 (128 x 4 x 2)
  float* pst2  = pst1 + 1024;      // 1024
  float* pst3  = pst2 + 1024;      // 1024
  float* peA   = pst3 + 1024;      // 32768
  float* peT   = peA + 32768;      // 3072
  // bf16 region
  unsigned short* xb0   = (unsigned short*)(peT + 3072);  // 32768
  unsigned short* abuf  = xb0 + 32768;                    // 32768
  unsigned short* mid   = abuf + 32768;                   // 131072
  unsigned short* saK   = mid + 131072;                   // 2 x [8][1536][32]
  unsigned short* saV   = saK + 2 * MAXS * 256;           // 2 x [256][1536]
  unsigned short* memK  = saV + 2 * MAXS * 256;           // 2 x [8][1024][32]
  unsigned short* memV  = memK + 2 * MEM_LEN * 256;       // 2 x [256][1024]
  unsigned short* dxdb  = memV + 2 * MEM_LEN * 256;       // 8 x [2][256][256]
  unsigned short* ffW1b = dxdb + 8 * 131072;
  unsigned short* ffW2b = ffW1b + 524288;
  unsigned short* inWb  = ffW2b + 524288;

  const dim3 blk(256);

  // ---- prologue ----
  cvt8_k<<<dim3(512, 1, 8), blk, 0, stream>>>(
      (const float*)d_in[8], (const float*)d_in[10], (const float*)d_in[12],
      (const float*)d_in[14], (const float*)d_in[16], (const float*)d_in[18],
      (const float*)d_in[20], (const float*)d_in[22], dxdb);
  cvtff_k<<<dim3(2048, 1, 2), blk, 0, stream>>>(ff_W1, ff_W2, ffW1b);
  cvtinw_k<<<160, blk, 0, stream>>>(in_W, inWb);
  pe_k<<<140, blk, 0, stream>>>(peA, peT);
  for (int l = 0; l < 2; ++l) {
    kvproj_k<2><<<dim3(16, 8), blk, 0, stream>>>(
        nullptr, 0, nullptr, nullptr, nullptr, nullptr, memory,
        dxdb + 5 * 131072 + l * 65536, ca_bk + l * 256,
        dxdb + 6 * 131072 + l * 65536, ca_bv + l * 256,
        memK + l * 262144, memV + l * 262144, MEM_LEN, 0);
  }
  hipMemcpyAsync(scene, last_pos, 256 * sizeof(float), hipMemcpyDeviceToDevice, stream);

  // ---- AR steps ----
  for (int s = 0; s < PRED; ++s) {
    embed_k<<<dim3(2, 4), blk, 0, stream>>>(scene, decoder_state, inWb, in_b,
                                            peA, peT, x0, xb0, s);
    for (int l = 0; l < 2; ++l) {
      const unsigned short* saWq = dxdb + 0 * 131072 + l * 65536;
      const unsigned short* saWk = dxdb + 1 * 131072 + l * 65536;
      const unsigned short* saWv = dxdb + 2 * 131072 + l * 65536;
      const unsigned short* saWo = dxdb + 3 * 131072 + l * 65536;
      const unsigned short* caWq = dxdb + 4 * 131072 + l * 65536;
      const unsigned short* caWo = dxdb + 7 * 131072 + l * 65536;
      unsigned short* saKl = saK + l * MAXS * 256;
      unsigned short* saVl = saV + l * MAXS * 256;
      unsigned short* memKl = memK + l * 262144;
      unsigned short* memVl = memV + l * 262144;

      if (l == 0) {
        kvproj_k<0><<<dim3(2, 8), blk, 0, stream>>>(
            xb0, 256, nullptr, nullptr, nullptr, nullptr, nullptr,
            saWk, sa_bk, saWv, sa_bv, saKl, saVl, MAXS, s * AGENTS);
        attn2_k<0><<<dim3(2, 8), blk, 0, stream>>>(
            xb0, nullptr, nullptr, nullptr, nullptr,
            saWq, sa_bq, saKl, saVl, agent_mask, abuf, (s + 1) * AGENTS, MAXS);
        wproj_k<0, 1, 0><<<dim3(2, 4), blk, 0, stream>>>(
            abuf, 256, nullptr, nullptr, nullptr, nullptr,
            saWo, sa_bo, 256, x0, nullptr, nullptr, nullptr, nullptr,
            Y1, pst1, nullptr);
      } else {
        kvproj_k<1><<<dim3(2, 8), blk, 0, stream>>>(
            nullptr, 0, Y3, pst3, ln3_g, ln3_b, nullptr,
            saWk, sa_bk + 256, saWv, sa_bv + 256, saKl, saVl, MAXS, s * AGENTS);
        attn2_k<1><<<dim3(2, 8), blk, 0, stream>>>(
            nullptr, Y3, pst3, ln3_g, ln3_b,
            saWq, sa_bq + 256, saKl, saVl, agent_mask, abuf, (s + 1) * AGENTS, MAXS);
        wproj_k<0, 2, 0><<<dim3(2, 4), blk, 0, stream>>>(
            abuf, 256, nullptr, nullptr, nullptr, nullptr,
            saWo, sa_bo + 256, 256, nullptr, Y3, pst3, ln3_g, ln3_b,
            Y1, pst1, nullptr);
      }
      attn2_k<1><<<dim3(2, 8), blk, 0, stream>>>(
          nullptr, Y1, pst1, ln1_g + l * 256, ln1_b + l * 256,
          caWq, ca_bq + l * 256, memKl, memVl, agent_mask, abuf, MEM_LEN, MEM_LEN);
      wproj_k<0, 2, 0><<<dim3(2, 4), blk, 0, stream>>>(
          abuf, 256, nullptr, nullptr, nullptr, nullptr,
          caWo, ca_bo + l * 256, 256, nullptr, Y1, pst1, ln1_g + l * 256, ln1_b + l * 256,
          Y2, pst2, nullptr);
      wproj_k<1, 0, 1><<<dim3(2, 16), blk, 0, stream>>>(
          nullptr, 0, Y2, pst2, ln2_g + l * 256, ln2_b + l * 256,
          ffW1b + l * 262144, ff_b1 + l * 1024, 256,
          nullptr, nullptr, nullptr, nullptr, nullptr,
          nullptr, nullptr, mid);
      wproj_k<0, 2, 0><<<dim3(2, 4), blk, 0, stream>>>(
          mid, 1024, nullptr, nullptr, nullptr, nullptr,
          ffW2b + l * 262144, ff_b2 + l * 256, 1024,
          nullptr, Y2, pst2, ln2_g + l * 256, ln2_b + l * 256,
          Y3, pst3, nullptr);
    }
    outp_k<<<1, blk, 0, stream>>>(Y3, pst3, ln3_g + 256, ln3_b + 256,
                                  out_W, out_b, out, scene, s);
  }
}